// Round 5
// baseline (257.998 us; speedup 1.0000x reference)
//
#include <hip/hip_runtime.h>

// Problem: N=8192, K=10, M=3. ALL FLOAT32 (settled R0-R4; R4 passed absmax=0).
//   o[n][m]    = max_k(|x[n,k]| + |w1[m,k]|)     (8192 x 3, all >= 0)
//   dist[i][j] = max_m(o[i][m] + o[j][m])        (8192 x 8192 fp32, 256 MB)
// R4 analysis: dist kernel ~90 us (~2.8 TB/s) vs harness fill at 6.6 TB/s.
// Limiters: (1) 160B-stride x-gather loads contending the TA pipe with
// stores, (2) 1 KB write runs with 32 KB row jumps.
// R5: stage o TRANSPOSED in d_ws (o_T[m][n]) -> column-o loads are fully
// coalesced float4 loads (no gather, no recompute); BJ=4096 tile with
// q-innermost stores -> 4 KB contiguous runs per wave per row.

#define N_ROWS 8192
#define K_DIM 10
#define M_DIM 3

#define BJ 4096  // columns per block (16 per thread, wave-strided)
#define BI 16    // rows per block

// ---------- Kernel 1: o_T[m][n] = max_k(|x[n,k]| + |w[m,k]|) ----------
__global__ void __launch_bounds__(256) o_kernel(
        const float* __restrict__ x,   // 8192 x 10
        const float* __restrict__ w,   // 3 x 10
        float* __restrict__ oT) {      // 3 x 8192 in d_ws
    const int n = blockIdx.x * 256 + threadIdx.x;
    if (n >= N_ROWS) return;

    float ax[K_DIM];
#pragma unroll
    for (int k = 0; k < K_DIM; ++k) ax[k] = fabsf(x[n * K_DIM + k]);

#pragma unroll
    for (int m = 0; m < M_DIM; ++m) {
        float best = -1e30f;
#pragma unroll
        for (int k = 0; k < K_DIM; ++k)
            best = fmaxf(best, ax[k] + fabsf(w[m * K_DIM + k]));
        oT[m * N_ROWS + n] = best;  // coalesced per m
    }
}

// ---------- Kernel 2: dist from o_T ----------
__global__ void __launch_bounds__(256) dist_kernel(
        const float* __restrict__ oT,  // 3 x 8192
        float4* __restrict__ dist) {   // 8192 x 2048 float4
    const int tid = threadIdx.x;
    const int wave = tid >> 6;
    const int lane = tid & 63;
    const int i0 = blockIdx.y * BI;
    // This thread's 4 float4 column-groups: j4base + q*64, q=0..3.
    const int j4base = blockIdx.x * (BJ / 4) + wave * 256 + lane;

    // Row o-values via LDS (48 uniform-ish loads, then broadcast reads).
    __shared__ float so[BI][M_DIM];
    if (tid < BI * M_DIM) {
        const int r = tid & (BI - 1);
        const int m = tid >> 4;  // BI == 16
        so[r][m] = oT[m * N_ROWS + i0 + r];
    }

    // Column o-values: 12 fully-coalesced float4 loads (1 KB/inst, L2-hit).
    const float4* oT4 = (const float4*)oT;
    float4 om[4][M_DIM];
#pragma unroll
    for (int q = 0; q < 4; ++q)
#pragma unroll
        for (int m = 0; m < M_DIM; ++m)
            om[q][m] = oT4[m * (N_ROWS / 4) + j4base + q * 64];

    __syncthreads();

    // Store loop: per wave, q-innermost gives 4 consecutive 1 KB chunks
    // (= 4 KB contiguous run) per row; 4 waves cover 16 KB of the row.
#pragma unroll
    for (int r = 0; r < BI; ++r) {
        const float a0 = so[r][0], a1 = so[r][1], a2 = so[r][2];
        const size_t rowbase = (size_t)(i0 + r) * (N_ROWS / 4);
#pragma unroll
        for (int q = 0; q < 4; ++q) {
            float4 v;
            v.x = fmaxf(fmaxf(a0 + om[q][0].x, a1 + om[q][1].x), a2 + om[q][2].x);
            v.y = fmaxf(fmaxf(a0 + om[q][0].y, a1 + om[q][1].y), a2 + om[q][2].y);
            v.z = fmaxf(fmaxf(a0 + om[q][0].z, a1 + om[q][1].z), a2 + om[q][2].z);
            v.w = fmaxf(fmaxf(a0 + om[q][0].w, a1 + om[q][1].w), a2 + om[q][2].w);
            dist[rowbase + j4base + q * 64] = v;
        }
    }
}

extern "C" void kernel_launch(void* const* d_in, const int* in_sizes, int n_in,
                              void* d_out, int out_size, void* d_ws, size_t ws_size,
                              hipStream_t stream) {
    const float* x = (const float*)d_in[0];  // 8192*10 fp32
    const float* w = (const float*)d_in[1];  // 3*10 fp32
    float* oT = (float*)d_ws;                // 3*8192 fp32 = 96 KB scratch
    (void)in_sizes; (void)n_in; (void)out_size; (void)ws_size;

    o_kernel<<<dim3(N_ROWS / 256), dim3(256), 0, stream>>>(x, w, oT);
    dist_kernel<<<dim3(N_ROWS / BJ, N_ROWS / BI), dim3(256), 0, stream>>>(
        oT, (float4*)d_out);
}